// Round 1
// baseline (407.803 us; speedup 1.0000x reference)
//
#include <hip/hip_runtime.h>
#include <hip/hip_bf16.h>
#include <stdint.h>

#define EPSV 1e-6f
#define N1 4096
#define N2 4096
#define DD 1024
#define NLAYERS 3
#define KKC 10

typedef __bf16 bf16_t;
typedef __bf16 bf16x8 __attribute__((ext_vector_type(8)));
typedef __bf16 bf16x4 __attribute__((ext_vector_type(4)));
typedef float f32x4 __attribute__((ext_vector_type(4)));

// ---------------- workspace layout (bytes) ----------------
#define OFF_CONSTS 0                                   // 256 floats: c[3] at 0..2, pk[3][11] at 8..
#define OFF_A      1024                                // a_tab[3][4096] f32
#define OFF_B      (OFF_A + NLAYERS*N1*4)              // b_tab[3][4096] f32
#define OFF_ZT     (((OFF_B + NLAYERS*N2*4) + 4095) & ~4095)
#define OFF_WT     (OFF_ZT + (size_t)N1*DD*2)
#define OFF_INTER  (OFF_WT + (size_t)N2*DD*2)
#define WS_FULL    (OFF_INTER + (size_t)N1*N2*2)
#define WS_MIN     OFF_INTER

__device__ __forceinline__ float softplusf(float x) {
  return fmaxf(x, 0.f) + log1pf(expf(-fabsf(x)));
}
__device__ __forceinline__ float wredsum(float x) {
  #pragma unroll
  for (int o = 32; o; o >>= 1) x += __shfl_xor(x, o, 64);
  return x;
}
__device__ __forceinline__ float wredmax(float x) {
  #pragma unroll
  for (int o = 32; o; o >>= 1) x = fmaxf(x, __shfl_xor(x, o, 64));
  return x;
}
__device__ __forceinline__ void global_load_lds16(const void* g, void* l) {
  __builtin_amdgcn_global_load_lds(
      (const __attribute__((address_space(1))) uint32_t*)g,
      (__attribute__((address_space(3))) uint32_t*)l, 16, 0, 0);
}

// ---------------- tiny kernels ----------------
__global__ void zero_out(float* out) { if (threadIdx.x == 0) out[0] = 0.f; }

__global__ __launch_bounds__(256) void prep_small(
    const float* __restrict__ lz, const float* __restrict__ lw,
    const float* __restrict__ pks, const float* __restrict__ Lp,
    float* __restrict__ consts, float* __restrict__ a_tab, float* __restrict__ b_tab)
{
  int n = blockIdx.x * blockDim.x + threadIdx.x;
  float Lv = softplusf(Lp[0]);
  if (n < N1) {
    float z0 = lz[n*3], z1 = lz[n*3+1], z2 = lz[n*3+2];
    float m = fmaxf(z0, fmaxf(z1, z2));
    float e0 = expf(z0-m), e1 = expf(z1-m), e2 = expf(z2-m);
    float inv = 1.f/(e0+e1+e2);
    a_tab[0*N1+n] = e0*inv*Lv; a_tab[1*N1+n] = e1*inv*Lv; a_tab[2*N1+n] = e2*inv*Lv;
    float w0 = lw[n*3], w1 = lw[n*3+1], w2 = lw[n*3+2];
    m = fmaxf(w0, fmaxf(w1, w2));
    e0 = expf(w0-m); e1 = expf(w1-m); e2 = expf(w2-m);
    inv = 1.f/(e0+e1+e2);
    b_tab[0*N2+n] = e0*inv+EPSV; b_tab[1*N2+n] = e1*inv+EPSV; b_tab[2*N2+n] = e2*inv+EPSV;
  }
  if (n < NLAYERS) {
    float p[KKC+1]; float m = -1e30f;
    for (int k = 0; k <= KKC; ++k) { p[k] = pks[n*(KKC+1)+k]; m = fmaxf(m, p[k]); }
    float s = 0.f;
    for (int k = 0; k <= KKC; ++k) { p[k] = expf(p[k]-m); s += p[k]; }
    float inv = 1.f/s;
    for (int k = 0; k <= KKC; ++k) consts[8 + n*(KKC+1) + k] = p[k]*inv;
    consts[n] = p[0]*inv + EPSV*(1.f - p[0]*inv);  // c = p0 + EPS*(1-p0)
  }
}

// one block per row: softmax; zmode=1 also applies the hierarchical kernel M via pyramid
__global__ __launch_bounds__(256) void prep_row(
    const float* __restrict__ src, bf16_t* __restrict__ dst,
    const float* __restrict__ consts, int layer, int zmode)
{
  __shared__ float sm[DD];
  __shared__ float pyr[1024];
  __shared__ float red[4];
  const int t = threadIdx.x;
  const int w = t >> 6, l = t & 63;
  const int n = blockIdx.x;
  const float4 u = ((const float4*)(src + (size_t)n*DD))[t];
  float mx = fmaxf(fmaxf(u.x, u.y), fmaxf(u.z, u.w));
  mx = wredmax(mx);
  if (l == 0) red[w] = mx;
  __syncthreads();
  mx = fmaxf(fmaxf(red[0], red[1]), fmaxf(red[2], red[3]));
  float e0 = expf(u.x-mx), e1 = expf(u.y-mx), e2 = expf(u.z-mx), e3 = expf(u.w-mx);
  float s = wredsum(e0+e1+e2+e3);
  __syncthreads();
  if (l == 0) red[w] = s;
  __syncthreads();
  float inv = 1.f/(red[0]+red[1]+red[2]+red[3]);
  e0 *= inv; e1 *= inv; e2 *= inv; e3 *= inv;
  if (!zmode) {
    bf16x4 o; o[0] = (bf16_t)e0; o[1] = (bf16_t)e1; o[2] = (bf16_t)e2; o[3] = (bf16_t)e3;
    *(bf16x4*)(dst + (size_t)n*DD + t*4) = o;
    return;
  }
  float4 f4; f4.x = e0; f4.y = e1; f4.z = e2; f4.w = e3;
  *(float4*)&sm[t*4] = f4;
  __syncthreads();
  // pyramid: level k block sums S_k (sizes 512,256,...,2)
  for (int idx = t; idx < 512; idx += 256) pyr[idx] = sm[2*idx] + sm[2*idx+1];
  __syncthreads();
  {
    if (t < 256) pyr[512+t]  = pyr[2*t]      + pyr[2*t+1];       __syncthreads();
    if (t < 128) pyr[768+t]  = pyr[512+2*t]  + pyr[512+2*t+1];   __syncthreads();
    if (t <  64) pyr[896+t]  = pyr[768+2*t]  + pyr[768+2*t+1];   __syncthreads();
    if (t <  32) pyr[960+t]  = pyr[896+2*t]  + pyr[896+2*t+1];   __syncthreads();
    if (t <  16) pyr[992+t]  = pyr[960+2*t]  + pyr[960+2*t+1];   __syncthreads();
    if (t <   8) pyr[1008+t] = pyr[992+2*t]  + pyr[992+2*t+1];   __syncthreads();
    if (t <   4) pyr[1016+t] = pyr[1008+2*t] + pyr[1008+2*t+1];  __syncthreads();
    if (t <   2) pyr[1020+t] = pyr[1016+2*t] + pyr[1016+2*t+1];  __syncthreads();
  }
  const float* pk = consts + 8 + layer*(KKC+1);
  const float p1 = pk[1], p2 = pk[2], p3 = pk[3], p4 = pk[4], p5 = pk[5];
  const float p6 = pk[6], p7 = pk[7], p8 = pk[8], p9 = pk[9], p10 = pk[10];
  #pragma unroll
  for (int q = 0; q < 4; ++q) {
    int j = t + q*256;
    float acc = p10*sm[j]
              + p1*pyr[(j>>1)]
              + p2*pyr[512 +(j>>2)]
              + p3*pyr[768 +(j>>3)]
              + p4*pyr[896 +(j>>4)]
              + p5*pyr[960 +(j>>5)]
              + p6*pyr[992 +(j>>6)]
              + p7*pyr[1008+(j>>7)]
              + p8*pyr[1016+(j>>8)]
              + p9*pyr[1020+(j>>9)];
    dst[(size_t)n*DD + j] = (bf16_t)acc;
  }
}

// ---------------- fused GEMM: C = Zt * W^T, epilogue softplus-sum + inter store ----------------
__global__ __launch_bounds__(256) void gemm_fused(
    const bf16_t* __restrict__ Az, const bf16_t* __restrict__ Bw,
    const float* __restrict__ a_tab, const float* __restrict__ b_tab,
    const float* __restrict__ gamma, const float* __restrict__ delta,
    const float* __restrict__ consts, int layer,
    bf16_t* __restrict__ inter, float* __restrict__ out)
{
  __shared__ bf16_t As[128*64];
  __shared__ bf16_t Bs[128*64];
  const int t = threadIdx.x;
  const int w = t >> 6, l = t & 63;
  const int wi = w >> 1, wj = w & 1;           // 2x2 wave grid, each wave owns 64x64
  const int fr = l & 15, fq = l >> 4;
  const int i0 = blockIdx.x * 128, j0 = blockIdx.y * 128;
  f32x4 zero = {0.f, 0.f, 0.f, 0.f};
  f32x4 acc[4][4];
  #pragma unroll
  for (int m = 0; m < 4; ++m)
    #pragma unroll
    for (int nn = 0; nn < 4; ++nn) acc[m][nn] = zero;

  const int srow = t >> 3;          // 0..31 (row within a 32-row staging slab)
  const int skk  = (t & 7) * 8;     // bf16 element offset in K
  const bf16_t* gA = Az + (size_t)(i0 + srow)*DD + skk;
  const bf16_t* gB = Bw + (size_t)(j0 + srow)*DD + skk;
  char* lA = (char*)As + w*1024;    // wave-uniform LDS bases; HW adds lane*16
  char* lB = (char*)Bs + w*1024;

  for (int k0 = 0; k0 < DD; k0 += 64) {
    __syncthreads();                 // prev iter's LDS reads done
    #pragma unroll
    for (int q = 0; q < 4; ++q) {
      global_load_lds16(gA + (size_t)q*32*DD + k0, lA + q*4096);
      global_load_lds16(gB + (size_t)q*32*DD + k0, lB + q*4096);
    }
    __syncthreads();                 // compiler drains vmcnt before s_barrier
    #pragma unroll
    for (int kc = 0; kc < 2; ++kc) {
      bf16x8 ar[4], br[4];
      #pragma unroll
      for (int m = 0; m < 4; ++m)
        ar[m] = *(const bf16x8*)(As + (wi*64 + m*16 + fr)*64 + kc*32 + fq*8);
      #pragma unroll
      for (int nn = 0; nn < 4; ++nn)
        br[nn] = *(const bf16x8*)(Bs + (wj*64 + nn*16 + fr)*64 + kc*32 + fq*8);
      #pragma unroll
      for (int m = 0; m < 4; ++m)
        #pragma unroll
        for (int nn = 0; nn < 4; ++nn)
          acc[m][nn] = __builtin_amdgcn_mfma_f32_16x16x32_bf16(ar[m], br[nn], acc[m][nn], 0, 0, 0);
    }
  }

  // epilogue: v = a*b*(dot+c) + g + d ; sum softplus(v) off-diagonal; store dot+c (bf16)
  const float cc = consts[layer];
  const float* at = a_tab + layer*N1;
  const float* bt = b_tab + layer*N2;
  float bv[4], dv[4];
  int colv[4];
  #pragma unroll
  for (int nn = 0; nn < 4; ++nn) {
    colv[nn] = j0 + wj*64 + nn*16 + fr;
    bv[nn] = bt[colv[nn]];
    dv[nn] = delta[colv[nn]*3 + layer];
  }
  float lsum = 0.f;
  #pragma unroll
  for (int m = 0; m < 4; ++m) {
    int rb = i0 + wi*64 + m*16 + fq*4;
    #pragma unroll
    for (int r = 0; r < 4; ++r) {
      int row = rb + r;
      float av = at[row];
      float gv = gamma[row*3 + layer];
      #pragma unroll
      for (int nn = 0; nn < 4; ++nn) {
        float dc = acc[m][nn][r] + cc;
        if (inter) inter[(size_t)row*N2 + colv[nn]] = (bf16_t)dc;
        float v = av*bv[nn]*dc + gv + dv[nn];
        if (row != colv[nn]) lsum += softplusf(v);
      }
    }
  }
  lsum = wredsum(lsum);
  __syncthreads();
  if (l == 0) ((float*)As)[w] = lsum;
  __syncthreads();
  if (t == 0) {
    float* r = (float*)As;
    atomicAdd(out, -(r[0] + r[1] + r[2] + r[3]));   // ll -= z_pdist1
  }
}

// ---------------- sparse: gather from materialized inter ----------------
__global__ __launch_bounds__(256) void sparse_gather(
    const int* __restrict__ is_, const int* __restrict__ js_,
    const bf16_t* __restrict__ inter,
    const float* __restrict__ a_tab, const float* __restrict__ b_tab,
    const float* __restrict__ gamma, const float* __restrict__ delta,
    int layer, int E, float* __restrict__ out)
{
  int e = blockIdx.x * blockDim.x + threadIdx.x;
  float v = 0.f;
  if (e < E) {
    int i = is_[e], j = js_[e];
    float dc = (float)inter[(size_t)i*N2 + j];
    v = a_tab[layer*N1+i] * b_tab[layer*N2+j] * dc + gamma[i*3+layer] + delta[j*3+layer];
  }
  v = wredsum(v);
  __shared__ float red[4];
  int w = threadIdx.x >> 6, l = threadIdx.x & 63;
  if (l == 0) red[w] = v;
  __syncthreads();
  if (threadIdx.x == 0) atomicAdd(out, red[0] + red[1] + red[2] + red[3]);
}

// ---------------- fallback sparse: per-edge dot (if ws too small for inter) ----------------
__global__ __launch_bounds__(256) void sparse_dot(
    const int* __restrict__ is_, const int* __restrict__ js_,
    const bf16_t* __restrict__ zt, const bf16_t* __restrict__ wt,
    const float* __restrict__ a_tab, const float* __restrict__ b_tab,
    const float* __restrict__ gamma, const float* __restrict__ delta,
    const float* __restrict__ consts, int layer, float* __restrict__ out)
{
  const int t = threadIdx.x, w = t >> 6, l = t & 63;
  const float cc = consts[layer];
  float accv = 0.f;
  for (int q = 0; q < 8; ++q) {
    int e = (blockIdx.x*4 + w)*8 + q;
    int i = is_[e], j = js_[e];
    const bf16x8* zr = (const bf16x8*)(zt + (size_t)i*DD) + l*2;
    const bf16x8* wr = (const bf16x8*)(wt + (size_t)j*DD) + l*2;
    float dot = 0.f;
    #pragma unroll
    for (int x = 0; x < 2; ++x) {
      bf16x8 a = zr[x], b = wr[x];
      #pragma unroll
      for (int y = 0; y < 8; ++y) dot += (float)a[y] * (float)b[y];
    }
    dot = wredsum(dot);
    if (l == 0)
      accv += a_tab[layer*N1+i]*b_tab[layer*N2+j]*(dot+cc) + gamma[i*3+layer] + delta[j*3+layer];
  }
  __shared__ float red[4];
  if (l == 0) red[w] = accv;
  __syncthreads();
  if (t == 0) atomicAdd(out, red[0] + red[1] + red[2] + red[3]);
}

extern "C" void kernel_launch(void* const* d_in, const int* in_sizes, int n_in,
                              void* d_out, int out_size, void* d_ws, size_t ws_size,
                              hipStream_t stream) {
  const float* us    = (const float*)d_in[0];
  const float* vs    = (const float*)d_in[1];
  const float* gamma = (const float*)d_in[2];
  const float* delta = (const float*)d_in[3];
  const float* lz    = (const float*)d_in[4];
  const float* lw    = (const float*)d_in[5];
  const float* pks   = (const float*)d_in[6];
  const float* Lp    = (const float*)d_in[7];
  const int*   sis   = (const int*)d_in[8];
  const int*   sjs   = (const int*)d_in[9];
  float* out = (float*)d_out;
  char*  ws  = (char*)d_ws;

  float*  consts = (float*)(ws + OFF_CONSTS);
  float*  a_tab  = (float*)(ws + OFF_A);
  float*  b_tab  = (float*)(ws + OFF_B);
  bf16_t* zt     = (bf16_t*)(ws + OFF_ZT);
  bf16_t* wt     = (bf16_t*)(ws + OFF_WT);
  bf16_t* inter  = (bf16_t*)(ws + OFF_INTER);
  const int E = in_sizes[8] / NLAYERS;
  if (ws_size < WS_MIN) return;               // cannot run at all
  const bool full = ws_size >= WS_FULL;

  zero_out<<<1, 64, 0, stream>>>(out);
  prep_small<<<(N1+255)/256, 256, 0, stream>>>(lz, lw, pks, Lp, consts, a_tab, b_tab);
  for (int lay = 0; lay < NLAYERS; ++lay) {
    prep_row<<<N1, 256, 0, stream>>>(us + (size_t)lay*N1*DD, zt, consts, lay, 1);
    prep_row<<<N2, 256, 0, stream>>>(vs + (size_t)lay*N2*DD, wt, consts, lay, 0);
    gemm_fused<<<dim3(32,32), 256, 0, stream>>>(zt, wt, a_tab, b_tab, gamma, delta,
                                                consts, lay, full ? inter : (bf16_t*)nullptr, out);
    if (full) {
      sparse_gather<<<(E+255)/256, 256, 0, stream>>>(sis + (size_t)lay*E, sjs + (size_t)lay*E,
                                                     inter, a_tab, b_tab, gamma, delta, lay, E, out);
    } else {
      sparse_dot<<<E/32, 256, 0, stream>>>(sis + (size_t)lay*E, sjs + (size_t)lay*E,
                                           zt, wt, a_tab, b_tab, gamma, delta, consts, lay, out);
    }
  }
}

// Round 2
// 248.531 us; speedup vs baseline: 1.6409x; 1.6409x over previous
//
#include <hip/hip_runtime.h>
#include <hip/hip_bf16.h>
#include <stdint.h>

#define EPSV 1e-6f
#define N1 4096
#define N2 4096
#define DD 1024
#define NLAYERS 3
#define KKC 10

typedef __bf16 bf16_t;
typedef __bf16 bf16x8 __attribute__((ext_vector_type(8)));
typedef __bf16 bf16x4 __attribute__((ext_vector_type(4)));
typedef float f32x4 __attribute__((ext_vector_type(4)));

// ---------------- workspace layout (bytes) ----------------
#define OFF_CONSTS 0                                   // c[3] at 0..2, pk[3][11] at 8..
#define OFF_A      1024                                // a_tab[3][4096] f32
#define OFF_B      (OFF_A + NLAYERS*N1*4)              // b_tab[3][4096] f32
#define OFF_ZT     (((OFF_B + NLAYERS*N2*4) + 4095) & ~4095)
// batched: zt[3], wt[3], inter[3]
#define ZT_LSTRIDE ((size_t)N1*DD)
#define IN_LSTRIDE ((size_t)N1*N2)
#define OFF_WT_B   (OFF_ZT + NLAYERS*ZT_LSTRIDE*2)
#define OFF_IN_B   (OFF_WT_B + NLAYERS*ZT_LSTRIDE*2)
#define WS_BATCH   (OFF_IN_B + NLAYERS*IN_LSTRIDE*2)
// per-layer fallback: zt, wt, inter (single layer)
#define OFF_WT_S   (OFF_ZT + ZT_LSTRIDE*2)
#define OFF_IN_S   (OFF_WT_S + ZT_LSTRIDE*2)
#define WS_FULL    (OFF_IN_S + IN_LSTRIDE*2)
#define WS_MIN     OFF_IN_S

__device__ __forceinline__ float softplus_fast(float x) {
  return fmaxf(x, 0.f) + __logf(1.f + __expf(-fabsf(x)));
}
__device__ __forceinline__ float softplus_ref(float x) {
  return fmaxf(x, 0.f) + log1pf(expf(-fabsf(x)));
}
__device__ __forceinline__ float wredsum(float x) {
  #pragma unroll
  for (int o = 32; o; o >>= 1) x += __shfl_xor(x, o, 64);
  return x;
}
__device__ __forceinline__ float wredmax(float x) {
  #pragma unroll
  for (int o = 32; o; o >>= 1) x = fmaxf(x, __shfl_xor(x, o, 64));
  return x;
}
__device__ __forceinline__ void global_load_lds16(const void* g, void* l) {
  __builtin_amdgcn_global_load_lds(
      (const __attribute__((address_space(1))) uint32_t*)g,
      (__attribute__((address_space(3))) uint32_t*)l, 16, 0, 0);
}

// ---------------- tiny kernels ----------------
__global__ void zero_out(float* out) { if (threadIdx.x == 0) out[0] = 0.f; }

__global__ __launch_bounds__(256) void prep_small(
    const float* __restrict__ lz, const float* __restrict__ lw,
    const float* __restrict__ pks, const float* __restrict__ Lp,
    float* __restrict__ consts, float* __restrict__ a_tab, float* __restrict__ b_tab)
{
  int n = blockIdx.x * blockDim.x + threadIdx.x;
  float Lv = softplus_ref(Lp[0]);
  if (n < N1) {
    float z0 = lz[n*3], z1 = lz[n*3+1], z2 = lz[n*3+2];
    float m = fmaxf(z0, fmaxf(z1, z2));
    float e0 = expf(z0-m), e1 = expf(z1-m), e2 = expf(z2-m);
    float inv = 1.f/(e0+e1+e2);
    a_tab[0*N1+n] = e0*inv*Lv; a_tab[1*N1+n] = e1*inv*Lv; a_tab[2*N1+n] = e2*inv*Lv;
    float w0 = lw[n*3], w1 = lw[n*3+1], w2 = lw[n*3+2];
    m = fmaxf(w0, fmaxf(w1, w2));
    e0 = expf(w0-m); e1 = expf(w1-m); e2 = expf(w2-m);
    inv = 1.f/(e0+e1+e2);
    b_tab[0*N2+n] = e0*inv+EPSV; b_tab[1*N2+n] = e1*inv+EPSV; b_tab[2*N2+n] = e2*inv+EPSV;
  }
  if (n < NLAYERS) {
    float p[KKC+1]; float m = -1e30f;
    for (int k = 0; k <= KKC; ++k) { p[k] = pks[n*(KKC+1)+k]; m = fmaxf(m, p[k]); }
    float s = 0.f;
    for (int k = 0; k <= KKC; ++k) { p[k] = expf(p[k]-m); s += p[k]; }
    float inv = 1.f/s;
    for (int k = 0; k <= KKC; ++k) consts[8 + n*(KKC+1) + k] = p[k]*inv;
    consts[n] = p[0]*inv + EPSV*(1.f - p[0]*inv);  // c = p0 + EPS*(1-p0)
  }
}

// grid (rows, layers): softmax; zmode=1 also applies hierarchical kernel M via pyramid.
// src row = us[(layer0+by)*N*DD + n*DD]; dst row = dst + by*dstLstride + n*DD.
__global__ __launch_bounds__(256) void prep_row(
    const float* __restrict__ src, bf16_t* __restrict__ dst, size_t dstLstride,
    const float* __restrict__ consts, int layer0, int zmode)
{
  __shared__ float sm[DD];
  __shared__ float pyr[1024];
  __shared__ float red[4];
  const int t = threadIdx.x;
  const int w = t >> 6, l = t & 63;
  const int n = blockIdx.x;
  const int layer = layer0 + blockIdx.y;
  src += (size_t)layer*N1*DD;
  dst += (size_t)blockIdx.y*dstLstride;
  const float4 u = ((const float4*)(src + (size_t)n*DD))[t];
  float mx = fmaxf(fmaxf(u.x, u.y), fmaxf(u.z, u.w));
  mx = wredmax(mx);
  if (l == 0) red[w] = mx;
  __syncthreads();
  mx = fmaxf(fmaxf(red[0], red[1]), fmaxf(red[2], red[3]));
  float e0 = expf(u.x-mx), e1 = expf(u.y-mx), e2 = expf(u.z-mx), e3 = expf(u.w-mx);
  float s = wredsum(e0+e1+e2+e3);
  __syncthreads();
  if (l == 0) red[w] = s;
  __syncthreads();
  float inv = 1.f/(red[0]+red[1]+red[2]+red[3]);
  e0 *= inv; e1 *= inv; e2 *= inv; e3 *= inv;
  if (!zmode) {
    bf16x4 o; o[0] = (bf16_t)e0; o[1] = (bf16_t)e1; o[2] = (bf16_t)e2; o[3] = (bf16_t)e3;
    *(bf16x4*)(dst + (size_t)n*DD + t*4) = o;
    return;
  }
  float4 f4; f4.x = e0; f4.y = e1; f4.z = e2; f4.w = e3;
  *(float4*)&sm[t*4] = f4;
  __syncthreads();
  for (int idx = t; idx < 512; idx += 256) pyr[idx] = sm[2*idx] + sm[2*idx+1];
  __syncthreads();
  {
    if (t < 256) pyr[512+t]  = pyr[2*t]      + pyr[2*t+1];       __syncthreads();
    if (t < 128) pyr[768+t]  = pyr[512+2*t]  + pyr[512+2*t+1];   __syncthreads();
    if (t <  64) pyr[896+t]  = pyr[768+2*t]  + pyr[768+2*t+1];   __syncthreads();
    if (t <  32) pyr[960+t]  = pyr[896+2*t]  + pyr[896+2*t+1];   __syncthreads();
    if (t <  16) pyr[992+t]  = pyr[960+2*t]  + pyr[960+2*t+1];   __syncthreads();
    if (t <   8) pyr[1008+t] = pyr[992+2*t]  + pyr[992+2*t+1];   __syncthreads();
    if (t <   4) pyr[1016+t] = pyr[1008+2*t] + pyr[1008+2*t+1];  __syncthreads();
    if (t <   2) pyr[1020+t] = pyr[1016+2*t] + pyr[1016+2*t+1];  __syncthreads();
  }
  const float* pk = consts + 8 + layer*(KKC+1);
  const float p1 = pk[1], p2 = pk[2], p3 = pk[3], p4 = pk[4], p5 = pk[5];
  const float p6 = pk[6], p7 = pk[7], p8 = pk[8], p9 = pk[9], p10 = pk[10];
  #pragma unroll
  for (int q = 0; q < 4; ++q) {
    int j = t + q*256;
    float acc = p10*sm[j]
              + p1*pyr[(j>>1)]
              + p2*pyr[512 +(j>>2)]
              + p3*pyr[768 +(j>>3)]
              + p4*pyr[896 +(j>>4)]
              + p5*pyr[960 +(j>>5)]
              + p6*pyr[992 +(j>>6)]
              + p7*pyr[1008+(j>>7)]
              + p8*pyr[1016+(j>>8)]
              + p9*pyr[1020+(j>>9)];
    dst[(size_t)n*DD + j] = (bf16_t)acc;
  }
}

// ---------------- fused GEMM (layer-batched): C = Zt*W^T; epilogue softplus-sum + inter store ----------------
__global__ __launch_bounds__(256) void gemm_fused(
    const bf16_t* __restrict__ Az, size_t zls,
    const bf16_t* __restrict__ Bw, size_t wls,
    const float* __restrict__ a_tab, const float* __restrict__ b_tab,
    const float* __restrict__ gamma, const float* __restrict__ delta,
    const float* __restrict__ consts, int layer0,
    bf16_t* __restrict__ inter, size_t ils, float* __restrict__ out)
{
  __shared__ bf16_t As[128*64];
  __shared__ bf16_t Bs[128*64];
  const int t = threadIdx.x;
  const int w = t >> 6, l = t & 63;
  const int wi = w >> 1, wj = w & 1;           // 2x2 wave grid, each wave owns 64x64
  const int fr = l & 15, fq = l >> 4;
  const int i0 = blockIdx.x * 128, j0 = blockIdx.y * 128;
  const int layer = layer0 + blockIdx.z;
  Az += (size_t)blockIdx.z * zls;
  Bw += (size_t)blockIdx.z * wls;
  if (inter) inter += (size_t)blockIdx.z * ils;
  f32x4 zero = {0.f, 0.f, 0.f, 0.f};
  f32x4 acc[4][4];
  #pragma unroll
  for (int m = 0; m < 4; ++m)
    #pragma unroll
    for (int nn = 0; nn < 4; ++nn) acc[m][nn] = zero;

  const int srow = t >> 3;                 // 0..31 staging row
  const int sg   = (t & 7) ^ (srow & 7);   // pre-swizzled global 16B-granule (T2, rule #21)
  const bf16_t* gA = Az + (size_t)(i0 + srow)*DD + sg*8;
  const bf16_t* gB = Bw + (size_t)(j0 + srow)*DD + sg*8;
  char* lA = (char*)As + w*1024;           // wave-uniform LDS bases; HW adds lane*16
  char* lB = (char*)Bs + w*1024;
  const int sxr = (fr & 7);                // read-side XOR granule

  for (int k0 = 0; k0 < DD; k0 += 64) {
    __syncthreads();
    #pragma unroll
    for (int q = 0; q < 4; ++q) {
      global_load_lds16(gA + (size_t)q*32*DD + k0, lA + q*4096);
      global_load_lds16(gB + (size_t)q*32*DD + k0, lB + q*4096);
    }
    __syncthreads();
    #pragma unroll
    for (int kc = 0; kc < 2; ++kc) {
      bf16x8 ar[4], br[4];
      #pragma unroll
      for (int m = 0; m < 4; ++m)
        ar[m] = *(const bf16x8*)(As + (wi*64 + m*16 + fr)*64 + (((kc*4+fq)^sxr)<<3));
      #pragma unroll
      for (int nn = 0; nn < 4; ++nn)
        br[nn] = *(const bf16x8*)(Bs + (wj*64 + nn*16 + fr)*64 + (((kc*4+fq)^sxr)<<3));
      #pragma unroll
      for (int m = 0; m < 4; ++m)
        #pragma unroll
        for (int nn = 0; nn < 4; ++nn)
          acc[m][nn] = __builtin_amdgcn_mfma_f32_16x16x32_bf16(ar[m], br[nn], acc[m][nn], 0, 0, 0);
    }
  }

  // epilogue: v = a*b*(dot+c) + g + d ; sum softplus(v) off-diagonal; store dot+c (bf16)
  const float cc = consts[layer];
  const float* at = a_tab + layer*N1;
  const float* bt = b_tab + layer*N2;
  float bv[4], dv[4];
  int colv[4];
  #pragma unroll
  for (int nn = 0; nn < 4; ++nn) {
    colv[nn] = j0 + wj*64 + nn*16 + fr;
    bv[nn] = bt[colv[nn]];
    dv[nn] = delta[colv[nn]*3 + layer];
  }
  float lsum = 0.f;
  #pragma unroll
  for (int m = 0; m < 4; ++m) {
    int rb = i0 + wi*64 + m*16 + fq*4;
    #pragma unroll
    for (int r = 0; r < 4; ++r) {
      int row = rb + r;
      float av = at[row];
      float gv = gamma[row*3 + layer];
      #pragma unroll
      for (int nn = 0; nn < 4; ++nn) {
        float dc = acc[m][nn][r] + cc;
        if (inter) inter[(size_t)row*N2 + colv[nn]] = (bf16_t)dc;
        float v = av*bv[nn]*dc + gv + dv[nn];
        if (row != colv[nn]) lsum += softplus_fast(v);
      }
    }
  }
  lsum = wredsum(lsum);
  __syncthreads();
  if (l == 0) ((float*)As)[w] = lsum;
  __syncthreads();
  if (t == 0) {
    float* r = (float*)As;
    atomicAdd(out, -(r[0] + r[1] + r[2] + r[3]));   // ll -= z_pdist1
  }
}

// ---------------- sparse: gather from materialized inter (layer-batched) ----------------
__global__ __launch_bounds__(256) void sparse_gather(
    const int* __restrict__ is_, const int* __restrict__ js_,
    const bf16_t* __restrict__ inter, size_t ils,
    const float* __restrict__ a_tab, const float* __restrict__ b_tab,
    const float* __restrict__ gamma, const float* __restrict__ delta,
    int layer0, int E, float* __restrict__ out)
{
  const int layer = layer0 + blockIdx.y;
  int e = blockIdx.x * blockDim.x + threadIdx.x;
  float v = 0.f;
  if (e < E) {
    int i = is_[(size_t)blockIdx.y*E + e], j = js_[(size_t)blockIdx.y*E + e];
    float dc = (float)inter[(size_t)blockIdx.y*ils + (size_t)i*N2 + j];
    v = a_tab[layer*N1+i] * b_tab[layer*N2+j] * dc + gamma[i*3+layer] + delta[j*3+layer];
  }
  v = wredsum(v);
  __shared__ float red[4];
  int w = threadIdx.x >> 6, l = threadIdx.x & 63;
  if (l == 0) red[w] = v;
  __syncthreads();
  if (threadIdx.x == 0) atomicAdd(out, red[0] + red[1] + red[2] + red[3]);
}

// ---------------- fallback sparse: per-edge dot (ws too small for inter) ----------------
__global__ __launch_bounds__(256) void sparse_dot(
    const int* __restrict__ is_, const int* __restrict__ js_,
    const bf16_t* __restrict__ zt, const bf16_t* __restrict__ wt,
    const float* __restrict__ a_tab, const float* __restrict__ b_tab,
    const float* __restrict__ gamma, const float* __restrict__ delta,
    const float* __restrict__ consts, int layer, float* __restrict__ out)
{
  const int t = threadIdx.x, w = t >> 6, l = t & 63;
  const float cc = consts[layer];
  float accv = 0.f;
  for (int q = 0; q < 8; ++q) {
    int e = (blockIdx.x*4 + w)*8 + q;
    int i = is_[e], j = js_[e];
    const bf16x8* zr = (const bf16x8*)(zt + (size_t)i*DD) + l*2;
    const bf16x8* wr = (const bf16x8*)(wt + (size_t)j*DD) + l*2;
    float dot = 0.f;
    #pragma unroll
    for (int x = 0; x < 2; ++x) {
      bf16x8 a = zr[x], b = wr[x];
      #pragma unroll
      for (int y = 0; y < 8; ++y) dot += (float)a[y] * (float)b[y];
    }
    dot = wredsum(dot);
    if (l == 0)
      accv += a_tab[layer*N1+i]*b_tab[layer*N2+j]*(dot+cc) + gamma[i*3+layer] + delta[j*3+layer];
  }
  __shared__ float red[4];
  if (l == 0) red[w] = accv;
  __syncthreads();
  if (t == 0) atomicAdd(out, red[0] + red[1] + red[2] + red[3]);
}

extern "C" void kernel_launch(void* const* d_in, const int* in_sizes, int n_in,
                              void* d_out, int out_size, void* d_ws, size_t ws_size,
                              hipStream_t stream) {
  const float* us    = (const float*)d_in[0];
  const float* vs    = (const float*)d_in[1];
  const float* gamma = (const float*)d_in[2];
  const float* delta = (const float*)d_in[3];
  const float* lz    = (const float*)d_in[4];
  const float* lw    = (const float*)d_in[5];
  const float* pks   = (const float*)d_in[6];
  const float* Lp    = (const float*)d_in[7];
  const int*   sis   = (const int*)d_in[8];
  const int*   sjs   = (const int*)d_in[9];
  float* out = (float*)d_out;
  char*  ws  = (char*)d_ws;

  float*  consts = (float*)(ws + OFF_CONSTS);
  float*  a_tab  = (float*)(ws + OFF_A);
  float*  b_tab  = (float*)(ws + OFF_B);
  const int E = in_sizes[8] / NLAYERS;
  if (ws_size < WS_MIN) return;

  zero_out<<<1, 64, 0, stream>>>(out);
  prep_small<<<(N1+255)/256, 256, 0, stream>>>(lz, lw, pks, Lp, consts, a_tab, b_tab);

  if (ws_size >= WS_BATCH) {
    // fully layer-batched path
    bf16_t* zt    = (bf16_t*)(ws + OFF_ZT);
    bf16_t* wt    = (bf16_t*)(ws + OFF_WT_B);
    bf16_t* inter = (bf16_t*)(ws + OFF_IN_B);
    prep_row<<<dim3(N1, NLAYERS), 256, 0, stream>>>(us, zt, ZT_LSTRIDE, consts, 0, 1);
    prep_row<<<dim3(N2, NLAYERS), 256, 0, stream>>>(vs, wt, ZT_LSTRIDE, consts, 0, 0);
    gemm_fused<<<dim3(32,32,NLAYERS), 256, 0, stream>>>(
        zt, ZT_LSTRIDE, wt, ZT_LSTRIDE, a_tab, b_tab, gamma, delta,
        consts, 0, inter, IN_LSTRIDE, out);
    sparse_gather<<<dim3((E+255)/256, NLAYERS), 256, 0, stream>>>(
        sis, sjs, inter, IN_LSTRIDE, a_tab, b_tab, gamma, delta, 0, E, out);
  } else {
    // per-layer fallback
    bf16_t* zt    = (bf16_t*)(ws + OFF_ZT);
    bf16_t* wt    = (bf16_t*)(ws + OFF_WT_S);
    bf16_t* inter = (bf16_t*)(ws + OFF_IN_S);
    const bool full = ws_size >= WS_FULL;
    for (int lay = 0; lay < NLAYERS; ++lay) {
      prep_row<<<dim3(N1,1), 256, 0, stream>>>(us, zt, 0, consts, lay, 1);
      prep_row<<<dim3(N2,1), 256, 0, stream>>>(vs, wt, 0, consts, lay, 0);
      gemm_fused<<<dim3(32,32,1), 256, 0, stream>>>(
          zt, 0, wt, 0, a_tab, b_tab, gamma, delta, consts, lay,
          full ? inter : (bf16_t*)nullptr, 0, out);
      if (full) {
        sparse_gather<<<dim3((E+255)/256,1), 256, 0, stream>>>(
            sis + (size_t)lay*E, sjs + (size_t)lay*E, inter, 0,
            a_tab, b_tab, gamma, delta, lay, E, out);
      } else {
        sparse_dot<<<E/32, 256, 0, stream>>>(
            sis + (size_t)lay*E, sjs + (size_t)lay*E, zt, wt,
            a_tab, b_tab, gamma, delta, consts, lay, out);
      }
    }
  }
}

// Round 3
// 222.744 us; speedup vs baseline: 1.8308x; 1.1158x over previous
//
#include <hip/hip_runtime.h>
#include <hip/hip_bf16.h>
#include <stdint.h>

#define EPSV 1e-6f
#define N1 4096
#define N2 4096
#define DD 1024
#define NLAYERS 3
#define KKC 10

typedef __bf16 bf16_t;
typedef __bf16 bf16x8 __attribute__((ext_vector_type(8)));
typedef __bf16 bf16x4 __attribute__((ext_vector_type(4)));
typedef float f32x4 __attribute__((ext_vector_type(4)));

// ---------------- workspace layout (bytes) ----------------
#define OFF_CONSTS 0                                   // c[3] at 0..2, pk[3][11] at 8..
#define OFF_A      1024                                // a_tab[3][4096] f32
#define OFF_B      (OFF_A + NLAYERS*N1*4)              // b_tab[3][4096] f32
#define OFF_ZT     (((OFF_B + NLAYERS*N2*4) + 4095) & ~4095)
#define ZT_LSTRIDE ((size_t)N1*DD)
#define IN_LSTRIDE ((size_t)N1*N2)
#define OFF_WT_B   (OFF_ZT + NLAYERS*ZT_LSTRIDE*2)
#define OFF_IN_B   (OFF_WT_B + NLAYERS*ZT_LSTRIDE*2)
#define WS_BATCH   (OFF_IN_B + NLAYERS*IN_LSTRIDE*2)
#define OFF_WT_S   (OFF_ZT + ZT_LSTRIDE*2)
#define OFF_IN_S   (OFF_WT_S + ZT_LSTRIDE*2)
#define WS_FULL    (OFF_IN_S + IN_LSTRIDE*2)
#define WS_MIN     OFF_IN_S

__device__ __forceinline__ float softplus_fast(float x) {
  return fmaxf(x, 0.f) + __logf(1.f + __expf(-fabsf(x)));
}
__device__ __forceinline__ float softplus_ref(float x) {
  return fmaxf(x, 0.f) + log1pf(expf(-fabsf(x)));
}
__device__ __forceinline__ float wredsum(float x) {
  #pragma unroll
  for (int o = 32; o; o >>= 1) x += __shfl_xor(x, o, 64);
  return x;
}
__device__ __forceinline__ float wredmax(float x) {
  #pragma unroll
  for (int o = 32; o; o >>= 1) x = fmaxf(x, __shfl_xor(x, o, 64));
  return x;
}
__device__ __forceinline__ void global_load_lds16(const void* g, void* l) {
  __builtin_amdgcn_global_load_lds(
      (const __attribute__((address_space(1))) uint32_t*)g,
      (__attribute__((address_space(3))) uint32_t*)l, 16, 0, 0);
}

// ---------------- tiny kernels ----------------
__global__ void zero_out(float* out) { if (threadIdx.x == 0) out[0] = 0.f; }

__global__ __launch_bounds__(256) void prep_small(
    const float* __restrict__ lz, const float* __restrict__ lw,
    const float* __restrict__ pks, const float* __restrict__ Lp,
    float* __restrict__ consts, float* __restrict__ a_tab, float* __restrict__ b_tab)
{
  int n = blockIdx.x * blockDim.x + threadIdx.x;
  float Lv = softplus_ref(Lp[0]);
  if (n < N1) {
    float z0 = lz[n*3], z1 = lz[n*3+1], z2 = lz[n*3+2];
    float m = fmaxf(z0, fmaxf(z1, z2));
    float e0 = expf(z0-m), e1 = expf(z1-m), e2 = expf(z2-m);
    float inv = 1.f/(e0+e1+e2);
    a_tab[0*N1+n] = e0*inv*Lv; a_tab[1*N1+n] = e1*inv*Lv; a_tab[2*N1+n] = e2*inv*Lv;
    float w0 = lw[n*3], w1 = lw[n*3+1], w2 = lw[n*3+2];
    m = fmaxf(w0, fmaxf(w1, w2));
    e0 = expf(w0-m); e1 = expf(w1-m); e2 = expf(w2-m);
    inv = 1.f/(e0+e1+e2);
    b_tab[0*N2+n] = e0*inv+EPSV; b_tab[1*N2+n] = e1*inv+EPSV; b_tab[2*N2+n] = e2*inv+EPSV;
  }
  if (n < NLAYERS) {
    float p[KKC+1]; float m = -1e30f;
    for (int k = 0; k <= KKC; ++k) { p[k] = pks[n*(KKC+1)+k]; m = fmaxf(m, p[k]); }
    float s = 0.f;
    for (int k = 0; k <= KKC; ++k) { p[k] = expf(p[k]-m); s += p[k]; }
    float inv = 1.f/s;
    for (int k = 0; k <= KKC; ++k) consts[8 + n*(KKC+1) + k] = p[k]*inv;
    consts[n] = p[0]*inv + EPSV*(1.f - p[0]*inv);  // c = p0 + EPS*(1-p0)
  }
}

// grid (rows, layers): softmax; zmode=1 also applies hierarchical kernel M via pyramid.
__global__ __launch_bounds__(256) void prep_row(
    const float* __restrict__ src, bf16_t* __restrict__ dst, size_t dstLstride,
    const float* __restrict__ consts, int layer0, int zmode)
{
  __shared__ float sm[DD];
  __shared__ float pyr[1024];
  __shared__ float red[4];
  const int t = threadIdx.x;
  const int w = t >> 6, l = t & 63;
  const int n = blockIdx.x;
  const int layer = layer0 + blockIdx.y;
  src += (size_t)layer*N1*DD;
  dst += (size_t)blockIdx.y*dstLstride;
  const float4 u = ((const float4*)(src + (size_t)n*DD))[t];
  float mx = fmaxf(fmaxf(u.x, u.y), fmaxf(u.z, u.w));
  mx = wredmax(mx);
  if (l == 0) red[w] = mx;
  __syncthreads();
  mx = fmaxf(fmaxf(red[0], red[1]), fmaxf(red[2], red[3]));
  float e0 = expf(u.x-mx), e1 = expf(u.y-mx), e2 = expf(u.z-mx), e3 = expf(u.w-mx);
  float s = wredsum(e0+e1+e2+e3);
  __syncthreads();
  if (l == 0) red[w] = s;
  __syncthreads();
  float inv = 1.f/(red[0]+red[1]+red[2]+red[3]);
  e0 *= inv; e1 *= inv; e2 *= inv; e3 *= inv;
  if (!zmode) {
    bf16x4 o; o[0] = (bf16_t)e0; o[1] = (bf16_t)e1; o[2] = (bf16_t)e2; o[3] = (bf16_t)e3;
    *(bf16x4*)(dst + (size_t)n*DD + t*4) = o;
    return;
  }
  float4 f4; f4.x = e0; f4.y = e1; f4.z = e2; f4.w = e3;
  *(float4*)&sm[t*4] = f4;
  __syncthreads();
  for (int idx = t; idx < 512; idx += 256) pyr[idx] = sm[2*idx] + sm[2*idx+1];
  __syncthreads();
  {
    if (t < 256) pyr[512+t]  = pyr[2*t]      + pyr[2*t+1];       __syncthreads();
    if (t < 128) pyr[768+t]  = pyr[512+2*t]  + pyr[512+2*t+1];   __syncthreads();
    if (t <  64) pyr[896+t]  = pyr[768+2*t]  + pyr[768+2*t+1];   __syncthreads();
    if (t <  32) pyr[960+t]  = pyr[896+2*t]  + pyr[896+2*t+1];   __syncthreads();
    if (t <  16) pyr[992+t]  = pyr[960+2*t]  + pyr[960+2*t+1];   __syncthreads();
    if (t <   8) pyr[1008+t] = pyr[992+2*t]  + pyr[992+2*t+1];   __syncthreads();
    if (t <   4) pyr[1016+t] = pyr[1008+2*t] + pyr[1008+2*t+1];  __syncthreads();
    if (t <   2) pyr[1020+t] = pyr[1016+2*t] + pyr[1016+2*t+1];  __syncthreads();
  }
  const float* pk = consts + 8 + layer*(KKC+1);
  const float p1 = pk[1], p2 = pk[2], p3 = pk[3], p4 = pk[4], p5 = pk[5];
  const float p6 = pk[6], p7 = pk[7], p8 = pk[8], p9 = pk[9], p10 = pk[10];
  #pragma unroll
  for (int q = 0; q < 4; ++q) {
    int j = t + q*256;
    float acc = p10*sm[j]
              + p1*pyr[(j>>1)]
              + p2*pyr[512 +(j>>2)]
              + p3*pyr[768 +(j>>3)]
              + p4*pyr[896 +(j>>4)]
              + p5*pyr[960 +(j>>5)]
              + p6*pyr[992 +(j>>6)]
              + p7*pyr[1008+(j>>7)]
              + p8*pyr[1016+(j>>8)]
              + p9*pyr[1020+(j>>9)];
    dst[(size_t)n*DD + j] = (bf16_t)acc;
  }
}

// ---------------- 256x256-tile pipelined GEMM + fused epilogue ----------------
// 8 waves (2M x 4N), each owns 128x64 of C. BK=32, double-buffered LDS (64KB),
// counted prefetch: stage(kt+1) issued right after the barrier that retires
// buf[(kt+1)&1]'s readers; consume(kt) guarded by own vmcnt(0) + barrier.
__device__ __forceinline__ void stage_tile(
    const bf16_t* __restrict__ Arows, const bf16_t* __restrict__ Brows,
    char* ldsbuf, int kelem, int w, int l)
{
  const int rl = w*16 + (l>>2);
  const int g  = l & 3;
  #pragma unroll
  for (int q = 0; q < 2; ++q) {
    const int row = q*128 + rl;
    const int gs = g ^ ((row>>1)&3);           // T2 swizzle (2-way balanced)
    global_load_lds16(Arows + (size_t)row*DD + kelem + gs*8,
                      ldsbuf + q*8192 + w*1024);
    global_load_lds16(Brows + (size_t)row*DD + kelem + gs*8,
                      ldsbuf + 16384 + q*8192 + w*1024);
  }
}

__global__ __launch_bounds__(512, 2) void gemm_fused(
    const bf16_t* __restrict__ Az, size_t zls,
    const bf16_t* __restrict__ Bw, size_t wls,
    const float* __restrict__ a_tab, const float* __restrict__ b_tab,
    const float* __restrict__ gamma, const float* __restrict__ delta,
    const float* __restrict__ consts, int layer0,
    bf16_t* __restrict__ inter, size_t ils, float* __restrict__ out)
{
  __shared__ bf16_t lds[2][16384];   // per buf: A[256][32] (16KB) then B[256][32]
  const int t = threadIdx.x;
  const int w = t >> 6, l = t & 63;
  const int wm = w >> 2, wn = w & 3;           // 2x4 wave grid; wave tile 128x64
  const int fr = l & 15, fq = l >> 4;
  const int i0 = blockIdx.x * 256, j0 = blockIdx.y * 256;
  const int layer = layer0 + blockIdx.z;
  Az += (size_t)blockIdx.z * zls + (size_t)i0 * DD;
  Bw += (size_t)blockIdx.z * wls + (size_t)j0 * DD;
  if (inter) inter += (size_t)blockIdx.z * ils;

  f32x4 acc[8][4];
  f32x4 zero = {0.f, 0.f, 0.f, 0.f};
  #pragma unroll
  for (int m = 0; m < 8; ++m)
    #pragma unroll
    for (int nn = 0; nn < 4; ++nn) acc[m][nn] = zero;

  stage_tile(Az, Bw, (char*)lds[0], 0, w, l);   // prologue: tile 0

  for (int kt = 0; kt < 32; ++kt) {
    asm volatile("s_waitcnt vmcnt(0)" ::: "memory");   // own tile-kt loads landed
    asm volatile("s_barrier" ::: "memory");            // all waves' tile-kt visible;
                                                       // buf[(kt+1)&1] readers (iter kt-1) done
    if (kt + 1 < 32)
      stage_tile(Az, Bw, (char*)lds[(kt+1)&1], (kt+1)*32, w, l);

    const bf16_t* Ab = lds[kt&1];
    const bf16_t* Bb = Ab + 8192;
    bf16x8 ar[8], br[4];
    #pragma unroll
    for (int m = 0; m < 8; ++m) {
      int r = wm*128 + m*16 + fr;
      int p = fq ^ ((r>>1)&3);
      ar[m] = *(const bf16x8*)(Ab + r*32 + p*8);
    }
    #pragma unroll
    for (int nn = 0; nn < 4; ++nn) {
      int r = wn*64 + nn*16 + fr;
      int p = fq ^ ((r>>1)&3);
      br[nn] = *(const bf16x8*)(Bb + r*32 + p*8);
    }
    __builtin_amdgcn_s_setprio(1);
    #pragma unroll
    for (int m = 0; m < 8; ++m)
      #pragma unroll
      for (int nn = 0; nn < 4; ++nn)
        acc[m][nn] = __builtin_amdgcn_mfma_f32_16x16x32_bf16(ar[m], br[nn], acc[m][nn], 0, 0, 0);
    __builtin_amdgcn_s_setprio(0);
  }

  // epilogue: v = a*b*(dot+c) + g + d ; sum softplus(v) off-diagonal; store dot+c
  const float cc = consts[layer];
  const float* at = a_tab + layer*N1;
  const float* bt = b_tab + layer*N2;
  float bv[4], dv[4];
  int colv[4];
  #pragma unroll
  for (int nn = 0; nn < 4; ++nn) {
    colv[nn] = j0 + wn*64 + nn*16 + fr;
    bv[nn] = bt[colv[nn]];
    dv[nn] = delta[colv[nn]*3 + layer];
  }
  float lsum = 0.f;
  #pragma unroll
  for (int m = 0; m < 8; ++m) {
    int rb = i0 + wm*128 + m*16 + fq*4;
    #pragma unroll
    for (int r = 0; r < 4; ++r) {
      int row = rb + r;
      float av = at[row];
      float gv = gamma[row*3 + layer];
      #pragma unroll
      for (int nn = 0; nn < 4; ++nn) {
        float dc = acc[m][nn][r] + cc;
        if (inter) inter[(size_t)row*N2 + colv[nn]] = (bf16_t)dc;
        float v = av*bv[nn]*dc + gv + dv[nn];
        if (row != colv[nn]) lsum += softplus_fast(v);
      }
    }
  }
  lsum = wredsum(lsum);
  __syncthreads();
  if (l == 0) ((float*)lds)[w] = lsum;
  __syncthreads();
  if (t == 0) {
    const float* r = (const float*)lds;
    float s = 0.f;
    #pragma unroll
    for (int i = 0; i < 8; ++i) s += r[i];
    atomicAdd(out, -s);   // ll -= z_pdist1
  }
}

// ---------------- sparse: gather from materialized inter (layer-batched) ----------------
__global__ __launch_bounds__(256) void sparse_gather(
    const int* __restrict__ is_, const int* __restrict__ js_,
    const bf16_t* __restrict__ inter, size_t ils,
    const float* __restrict__ a_tab, const float* __restrict__ b_tab,
    const float* __restrict__ gamma, const float* __restrict__ delta,
    int layer0, int E, float* __restrict__ out)
{
  const int layer = layer0 + blockIdx.y;
  int e = blockIdx.x * blockDim.x + threadIdx.x;
  float v = 0.f;
  if (e < E) {
    int i = is_[(size_t)blockIdx.y*E + e], j = js_[(size_t)blockIdx.y*E + e];
    float dc = (float)inter[(size_t)blockIdx.y*ils + (size_t)i*N2 + j];
    v = a_tab[layer*N1+i] * b_tab[layer*N2+j] * dc + gamma[i*3+layer] + delta[j*3+layer];
  }
  v = wredsum(v);
  __shared__ float red[4];
  int w = threadIdx.x >> 6, l = threadIdx.x & 63;
  if (l == 0) red[w] = v;
  __syncthreads();
  if (threadIdx.x == 0) atomicAdd(out, red[0] + red[1] + red[2] + red[3]);
}

// ---------------- fallback sparse: per-edge dot (ws too small for inter) ----------------
__global__ __launch_bounds__(256) void sparse_dot(
    const int* __restrict__ is_, const int* __restrict__ js_,
    const bf16_t* __restrict__ zt, const bf16_t* __restrict__ wt,
    const float* __restrict__ a_tab, const float* __restrict__ b_tab,
    const float* __restrict__ gamma, const float* __restrict__ delta,
    const float* __restrict__ consts, int layer, float* __restrict__ out)
{
  const int t = threadIdx.x, w = t >> 6, l = t & 63;
  const float cc = consts[layer];
  float accv = 0.f;
  for (int q = 0; q < 8; ++q) {
    int e = (blockIdx.x*4 + w)*8 + q;
    int i = is_[e], j = js_[e];
    const bf16x8* zr = (const bf16x8*)(zt + (size_t)i*DD) + l*2;
    const bf16x8* wr = (const bf16x8*)(wt + (size_t)j*DD) + l*2;
    float dot = 0.f;
    #pragma unroll
    for (int x = 0; x < 2; ++x) {
      bf16x8 a = zr[x], b = wr[x];
      #pragma unroll
      for (int y = 0; y < 8; ++y) dot += (float)a[y] * (float)b[y];
    }
    dot = wredsum(dot);
    if (l == 0)
      accv += a_tab[layer*N1+i]*b_tab[layer*N2+j]*(dot+cc) + gamma[i*3+layer] + delta[j*3+layer];
  }
  __shared__ float red[4];
  if (l == 0) red[w] = accv;
  __syncthreads();
  if (t == 0) atomicAdd(out, red[0] + red[1] + red[2] + red[3]);
}

extern "C" void kernel_launch(void* const* d_in, const int* in_sizes, int n_in,
                              void* d_out, int out_size, void* d_ws, size_t ws_size,
                              hipStream_t stream) {
  const float* us    = (const float*)d_in[0];
  const float* vs    = (const float*)d_in[1];
  const float* gamma = (const float*)d_in[2];
  const float* delta = (const float*)d_in[3];
  const float* lz    = (const float*)d_in[4];
  const float* lw    = (const float*)d_in[5];
  const float* pks   = (const float*)d_in[6];
  const float* Lp    = (const float*)d_in[7];
  const int*   sis   = (const int*)d_in[8];
  const int*   sjs   = (const int*)d_in[9];
  float* out = (float*)d_out;
  char*  ws  = (char*)d_ws;

  float*  consts = (float*)(ws + OFF_CONSTS);
  float*  a_tab  = (float*)(ws + OFF_A);
  float*  b_tab  = (float*)(ws + OFF_B);
  const int E = in_sizes[8] / NLAYERS;
  if (ws_size < WS_MIN) return;

  zero_out<<<1, 64, 0, stream>>>(out);
  prep_small<<<(N1+255)/256, 256, 0, stream>>>(lz, lw, pks, Lp, consts, a_tab, b_tab);

  if (ws_size >= WS_BATCH) {
    bf16_t* zt    = (bf16_t*)(ws + OFF_ZT);
    bf16_t* wt    = (bf16_t*)(ws + OFF_WT_B);
    bf16_t* inter = (bf16_t*)(ws + OFF_IN_B);
    prep_row<<<dim3(N1, NLAYERS), 256, 0, stream>>>(us, zt, ZT_LSTRIDE, consts, 0, 1);
    prep_row<<<dim3(N2, NLAYERS), 256, 0, stream>>>(vs, wt, ZT_LSTRIDE, consts, 0, 0);
    gemm_fused<<<dim3(16,16,NLAYERS), 512, 0, stream>>>(
        zt, ZT_LSTRIDE, wt, ZT_LSTRIDE, a_tab, b_tab, gamma, delta,
        consts, 0, inter, IN_LSTRIDE, out);
    sparse_gather<<<dim3((E+255)/256, NLAYERS), 256, 0, stream>>>(
        sis, sjs, inter, IN_LSTRIDE, a_tab, b_tab, gamma, delta, 0, E, out);
  } else {
    bf16_t* zt    = (bf16_t*)(ws + OFF_ZT);
    bf16_t* wt    = (bf16_t*)(ws + OFF_WT_S);
    bf16_t* inter = (bf16_t*)(ws + OFF_IN_S);
    const bool full = ws_size >= WS_FULL;
    for (int lay = 0; lay < NLAYERS; ++lay) {
      prep_row<<<dim3(N1,1), 256, 0, stream>>>(us, zt, 0, consts, lay, 1);
      prep_row<<<dim3(N2,1), 256, 0, stream>>>(vs, wt, 0, consts, lay, 0);
      gemm_fused<<<dim3(16,16,1), 512, 0, stream>>>(
          zt, 0, wt, 0, a_tab, b_tab, gamma, delta, consts, lay,
          full ? inter : (bf16_t*)nullptr, 0, out);
      if (full) {
        sparse_gather<<<dim3((E+255)/256,1), 256, 0, stream>>>(
            sis + (size_t)lay*E, sjs + (size_t)lay*E, inter, 0,
            a_tab, b_tab, gamma, delta, lay, E, out);
      } else {
        sparse_dot<<<E/32, 256, 0, stream>>>(
            sis + (size_t)lay*E, sjs + (size_t)lay*E, zt, wt,
            a_tab, b_tab, gamma, delta, consts, lay, out);
      }
    }
  }
}